// Round 2
// baseline (152.734 us; speedup 1.0000x reference)
//
#include <hip/hip_runtime.h>
#include <hip/hip_cooperative_groups.h>

namespace cg = cooperative_groups;

// EncoderBlock, fused via cooperative launch:
//   gather(x, idx) -> per-o GEMM (512x128 @ K=512) + bias -> BN(B=512) -> SiLU.
// Grid 256 blocks x 256 threads (one block per (o, 128-batch tile), 1 block/CU,
// all 256 CUs active). Depth-2 register prefetch + double-buffered LDS with ONE
// barrier per K-step hides HBM latency. Column partial stats -> ws ->
// grid.sync() -> scale/shift -> normalize accumulators IN REGISTERS -> store.
// No y intermediate, no second kernel.

typedef __attribute__((ext_vector_type(8))) __bf16 bf16x8;
typedef __attribute__((ext_vector_type(4))) __bf16 bf16x4;
typedef __attribute__((ext_vector_type(4))) float  f32x4;

#define N_IN   64
#define D_IN   128
#define FEAT   8192            // 64 * 128
#define LDA    40              // LDS row stride (bf16): 80B, 16B-aligned

struct Stage {
    f32x4 a[4];    // 16 floats of x (one 32-k chunk slice)
    f32x4 w[4];    // 4 tasks x 4 strided W scalars
};

__global__ __launch_bounds__(256, 1)
void fused_encoder_coop(const float* __restrict__ x, const float* __restrict__ W,
                        const float* __restrict__ bias, const float* __restrict__ gamma,
                        const float* __restrict__ beta, const int* __restrict__ idxp,
                        float* __restrict__ out, float* __restrict__ psum,
                        float* __restrict__ psq)
{
    __shared__ __bf16 Alds[2][128 * LDA];   // 2 x 10 KiB
    __shared__ __bf16 Blds[2][128 * LDA];   // 2 x 10 KiB
    __shared__ float  sscale[128];
    __shared__ float  sshift[128];

    // XCD-aware decode: the 4 batch-tiles of one o land on the same XCD
    // (shared 262 KB W[o] panel stays L2-resident).
    const int bid = blockIdx.x;
    const int xcd = bid & 7;
    const int jj  = bid >> 3;              // 0..31
    const int o   = (jj >> 2) * 8 + xcd;   // bijective over 0..63
    const int bt  = jj & 3;
    const int b0  = bt * 128;

    const int tid  = threadIdx.x;
    const int wave = tid >> 6;
    const int lane = tid & 63;
    const int wr   = wave >> 1;            // 0..1: row group (64 rows)
    const int wc   = wave & 1;             // col group (64 cols)
    const int lam  = lane & 15;
    const int quad = lane >> 4;

    int rsel[4];
#pragma unroll
    for (int k = 0; k < 4; ++k) rsel[k] = idxp[o * 4 + k];

    const f32x4 zero4 = {0.f, 0.f, 0.f, 0.f};
    f32x4 acc[4][4];
#pragma unroll
    for (int mi = 0; mi < 4; ++mi)
#pragma unroll
        for (int ni = 0; ni < 4; ++ni) acc[mi][ni] = zero4;

    // A staging: 2 threads/row, 16 floats each (128 rows x 32 k)
    const int m_a = tid >> 1;              // 0..127
    const int ca  = (tid & 1) * 16;
    // B staging: 4 tasks/thread over (128 e x 8 k-groups)
    int te[4], tdg[4];
#pragma unroll
    for (int it = 0; it < 4; ++it) {
        const int task = it * 256 + tid;
        te[it]  = task & 127;
        tdg[it] = task >> 7;
    }

    Stage s0, s1;

    auto load_stage = [&](Stage& S, const int kkc) {
        const int kidx = kkc >> 2;
        const int d0   = (kkc & 3) * 32;
        const float* xa = x + (((b0 + m_a) * N_IN + rsel[kidx]) * D_IN + d0 + ca);
#pragma unroll
        for (int v = 0; v < 4; ++v) S.a[v] = *(const f32x4*)(xa + v * 4);
        const float* wb = W + (((o * 4 + kidx) * 128 + d0) * 128);
#pragma unroll
        for (int it = 0; it < 4; ++it) {
            const float* wp = wb + tdg[it] * 4 * 128 + te[it];
            f32x4 t;
            t[0] = wp[0]; t[1] = wp[128]; t[2] = wp[256]; t[3] = wp[384];
            S.w[it] = t;
        }
    };

    auto store_stage = [&](const Stage& S, const int buf) {
        bf16x8 p0, p1;
#pragma unroll
        for (int j = 0; j < 4; ++j) {
            p0[j]     = (__bf16)S.a[0][j];
            p0[j + 4] = (__bf16)S.a[1][j];
            p1[j]     = (__bf16)S.a[2][j];
            p1[j + 4] = (__bf16)S.a[3][j];
        }
        *(bf16x8*)&Alds[buf][m_a * LDA + ca]     = p0;
        *(bf16x8*)&Alds[buf][m_a * LDA + ca + 8] = p1;
#pragma unroll
        for (int it = 0; it < 4; ++it) {
            bf16x4 q;
#pragma unroll
            for (int j = 0; j < 4; ++j) q[j] = (__bf16)S.w[it][j];
            *(bf16x4*)&Blds[buf][te[it] * LDA + tdg[it] * 4] = q;
        }
    };

    auto compute = [&](const int buf) {
        bf16x8 af[4], bfv[4];
#pragma unroll
        for (int mi = 0; mi < 4; ++mi)
            af[mi] = *(const bf16x8*)&Alds[buf][(wr * 64 + mi * 16 + lam) * LDA + quad * 8];
#pragma unroll
        for (int ni = 0; ni < 4; ++ni)
            bfv[ni] = *(const bf16x8*)&Blds[buf][(wc * 64 + ni * 16 + lam) * LDA + quad * 8];
#pragma unroll
        for (int mi = 0; mi < 4; ++mi)
#pragma unroll
            for (int ni = 0; ni < 4; ++ni)
                acc[mi][ni] = __builtin_amdgcn_mfma_f32_16x16x32_bf16(
                    af[mi], bfv[ni], acc[mi][ni], 0, 0, 0);
    };

    // Pipeline: data j lives in stage (j&1) and LDS buffer (j&1).
    load_stage(s0, 0);
    load_stage(s1, 1);
    store_stage(s0, 0);        // vmcnt wait for stage-0 only; stage-1 stays in flight
    __syncthreads();

#pragma unroll
    for (int kk = 0; kk < 16; ++kk) {
        if (kk + 2 < 16) {                 // issue loads for kk+2 (slot free: kk stored)
            if (kk & 1) load_stage(s1, kk + 2);
            else        load_stage(s0, kk + 2);
        }
        compute(kk & 1);                   // lgkm waits only
        if (kk + 1 < 16) {                 // store kk+1 (its loads are 1 iter old)
            if (kk & 1) store_stage(s0, (kk + 1) & 1);
            else        store_stage(s1, (kk + 1) & 1);
            __syncthreads();               // one barrier per K-step
        }
    }

    // ---- bias (before BN, matching reference) ----
    const int nbase = wc * 64;
    float bvals[4];
#pragma unroll
    for (int ni = 0; ni < 4; ++ni)
        bvals[ni] = bias[o * 128 + nbase + ni * 16 + lam];
#pragma unroll
    for (int mi = 0; mi < 4; ++mi)
#pragma unroll
        for (int ni = 0; ni < 4; ++ni)
#pragma unroll
            for (int rr = 0; rr < 4; ++rr) acc[mi][ni][rr] += bvals[ni];

    // ---- per-column partials over this wave's 64 rows -> global ws ----
#pragma unroll
    for (int ni = 0; ni < 4; ++ni) {
        float s = 0.f, q = 0.f;
#pragma unroll
        for (int mi = 0; mi < 4; ++mi)
#pragma unroll
            for (int rr = 0; rr < 4; ++rr) {
                const float v = acc[mi][ni][rr];
                s += v; q += v * v;
            }
        s += __shfl_xor(s, 16); s += __shfl_xor(s, 32);
        q += __shfl_xor(q, 16); q += __shfl_xor(q, 32);
        if (quad == 0) {
            const int slot = bt * 2 + wr;          // 8 slots of 64 rows per o
            const int e    = nbase + ni * 16 + lam;
            psum[(o * 8 + slot) * 128 + e] = s;
            psq [(o * 8 + slot) * 128 + e] = q;
        }
    }

    __threadfence();
    cg::this_grid().sync();

    // ---- scale/shift for this o ----
    if (tid < 128) {
        float s = 0.f, q = 0.f;
#pragma unroll
        for (int sl = 0; sl < 8; ++sl) {
            s += psum[(o * 8 + sl) * 128 + tid];
            q += psq [(o * 8 + sl) * 128 + tid];
        }
        const float mean = s * (1.0f / 512.0f);
        const float var  = q * (1.0f / 512.0f) - mean * mean;
        const float rstd = rsqrtf(var + 1e-5f);
        const float sc   = rstd * gamma[o * 128 + tid];
        sscale[tid] = sc;
        sshift[tid] = beta[o * 128 + tid] - mean * sc;
    }
    __syncthreads();

    // ---- normalize + SiLU in-register, single fp32 store ----
#pragma unroll
    for (int mi = 0; mi < 4; ++mi) {
        const int rowb = b0 + wr * 64 + mi * 16 + quad * 4;
#pragma unroll
        for (int ni = 0; ni < 4; ++ni) {
            const int col = nbase + ni * 16 + lam;
            const float sc = sscale[col];
            const float sh = sshift[col];
#pragma unroll
            for (int rr = 0; rr < 4; ++rr) {
                const float xn = acc[mi][ni][rr] * sc + sh;
                const float sg = 1.0f / (1.0f + __expf(-xn));
                out[(rowb + rr) * FEAT + o * 128 + col] = xn * sg;
            }
        }
    }
}

extern "C" void kernel_launch(void* const* d_in, const int* in_sizes, int n_in,
                              void* d_out, int out_size, void* d_ws, size_t ws_size,
                              hipStream_t stream)
{
    const float* x     = (const float*)d_in[0];
    const float* W     = (const float*)d_in[1];
    const float* bias  = (const float*)d_in[2];
    const float* gamma = (const float*)d_in[3];
    const float* beta  = (const float*)d_in[4];
    const int*   idx   = (const int*)d_in[5];
    float* out  = (float*)d_out;
    float* psum = (float*)d_ws;                 // 64*8*128 f32 = 256 KiB
    float* psq  = psum + 64 * 8 * 128;          // 256 KiB

    void* args[] = {&x, &W, &bias, &gamma, &beta, &idx, &out, &psum, &psq};
    hipLaunchCooperativeKernel((const void*)fused_encoder_coop,
                               dim3(256), dim3(256), args, 0, stream);
}

// Round 3
// 104.047 us; speedup vs baseline: 1.4679x; 1.4679x over previous
//
#include <hip/hip_runtime.h>

// EncoderBlock, single fused kernel, BN block-local:
//   gather(x, idx) -> GEMM slice (M=512 batches x N=32 cols @ K=512) + bias
//   -> BN stats over the block's own 512 rows -> SiLU -> fp32 out.
// Grid: 256 blocks = (o, 32-col slice). 1024 threads = 16 waves (4/SIMD).
// K-loop: depth-2 register prefetch, double-buffered LDS, ONE raw s_barrier
// per step with counted vmcnt (compiler auto-waits; NO vmcnt(0) drain since
// we never call __syncthreads inside the loop). No workspace, no 2nd kernel.

typedef __attribute__((ext_vector_type(8))) __bf16 bf16x8;
typedef __attribute__((ext_vector_type(4))) float  f32x4;

#define FEAT 8192
#define LDA  40              // LDS row stride (bf16): 80B, 16B-aligned

// lgkmcnt(0): our ds_writes visible; raw s_barrier: no vmcnt(0) drain, so
// prefetch global loads stay in flight across the barrier (T4).
// sched_barrier(0) fences pin ordering (guide rule #18).
#define PIPE_BARRIER() do { \
    __builtin_amdgcn_sched_barrier(0); \
    asm volatile("s_waitcnt lgkmcnt(0)" ::: "memory"); \
    __builtin_amdgcn_s_barrier(); \
    __builtin_amdgcn_sched_barrier(0); \
} while (0)

__global__ __launch_bounds__(1024, 4)
void fused_encoder(const float* __restrict__ x, const float* __restrict__ W,
                   const float* __restrict__ bias, const float* __restrict__ gamma,
                   const float* __restrict__ beta, const int* __restrict__ idxp,
                   float* __restrict__ out)
{
    __shared__ alignas(16) __bf16 Alds[2][512 * LDA];   // 2 x 40 KiB
    __shared__ alignas(16) __bf16 Blds[2][32 * LDA];    // 2 x 2.5 KiB
    __shared__ float Sred[16][32];
    __shared__ float Qred[16][32];
    __shared__ float sscale[32];
    __shared__ float sshift[32];

    // XCD-aware decode: 4 col-slices of one o share an XCD (shared A panel in L2)
    const int bid = blockIdx.x;
    const int o   = ((bid >> 5) << 3) | (bid & 7);
    const int es  = (bid >> 3) & 3;
    const int e0  = es * 32;

    const int tid  = threadIdx.x;
    const int wave = tid >> 6;          // 0..15 -> rows wave*32 .. +31
    const int lane = tid & 63;
    const int lam  = lane & 15;
    const int quad = lane >> 4;

    int rsel[4];
#pragma unroll
    for (int k = 0; k < 4; ++k) rsel[k] = idxp[o * 4 + k];

    const f32x4 zero4 = {0.f, 0.f, 0.f, 0.f};
    f32x4 acc[2][2];
#pragma unroll
    for (int mi = 0; mi < 2; ++mi)
#pragma unroll
        for (int ni = 0; ni < 2; ++ni) acc[mi][ni] = zero4;

    // A staging: 2 threads/row, 16 floats each (512 rows x 32 k)
    const int m_a = tid >> 1;           // 0..511
    const int ca  = (tid & 1) * 16;
    // B staging: 1 float/thread (32 e x 32 k)
    const int e_b = tid & 31;
    const int d_b = tid >> 5;           // 0..31

    // register prefetch stages (named, statically indexed — no scratch)
    f32x4 sA0[4], sA1[4];
    float sB0, sB1;

    auto load_stage = [&](f32x4 (&SA)[4], float& SB, const int kkc) {
        const int kidx  = kkc >> 2;
        const int dbase = (kkc & 3) * 32;
        const float* xa = x + ((m_a * 64 + rsel[kidx]) * 128 + dbase + ca);
#pragma unroll
        for (int v = 0; v < 4; ++v) SA[v] = *(const f32x4*)(xa + v * 4);
        SB = W[(((o * 4 + kidx) * 128) + dbase + d_b) * 128 + e0 + e_b];
    };

    auto store_stage = [&](const f32x4 (&SA)[4], const float SB, const int buf) {
        bf16x8 p0, p1;
#pragma unroll
        for (int j = 0; j < 4; ++j) {
            p0[j]     = (__bf16)SA[0][j];
            p0[j + 4] = (__bf16)SA[1][j];
            p1[j]     = (__bf16)SA[2][j];
            p1[j + 4] = (__bf16)SA[3][j];
        }
        *(bf16x8*)&Alds[buf][m_a * LDA + ca]     = p0;
        *(bf16x8*)&Alds[buf][m_a * LDA + ca + 8] = p1;
        Blds[buf][e_b * LDA + d_b] = (__bf16)SB;
    };

    auto compute = [&](const int buf) {
        bf16x8 af[2], bfr[2];
#pragma unroll
        for (int mi = 0; mi < 2; ++mi)
            af[mi] = *(const bf16x8*)&Alds[buf][(wave * 32 + mi * 16 + lam) * LDA + quad * 8];
#pragma unroll
        for (int ni = 0; ni < 2; ++ni)
            bfr[ni] = *(const bf16x8*)&Blds[buf][(ni * 16 + lam) * LDA + quad * 8];
#pragma unroll
        for (int mi = 0; mi < 2; ++mi)
#pragma unroll
            for (int ni = 0; ni < 2; ++ni)
                acc[mi][ni] = __builtin_amdgcn_mfma_f32_16x16x32_bf16(
                    af[mi], bfr[ni], acc[mi][ni], 0, 0, 0);
    };

    // ---- pipeline: data kk lives in stage/buf (kk & 1) ----
    load_stage(sA0, sB0, 0);
    load_stage(sA1, sB1, 1);
    store_stage(sA0, sB0, 0);   // waits vmcnt for stage-0 only; stage-1 in flight
    PIPE_BARRIER();

#pragma unroll
    for (int kk = 0; kk < 16; ++kk) {
        if (kk + 2 < 16) {                     // issue loads for kk+2
            if ((kk & 1) == 0) load_stage(sA0, sB0, kk + 2);
            else               load_stage(sA1, sB1, kk + 2);
        }
        __builtin_amdgcn_sched_barrier(0);     // pin load issue before compute
        compute(kk & 1);
        if (kk + 1 < 16) {                     // stage kk+1 -> buf (kk+1)&1
            if ((kk & 1) == 0) store_stage(sA1, sB1, 1);
            else               store_stage(sA0, sB0, 0);
            PIPE_BARRIER();
        }
    }

    // ---- bias ----
    float bvals[2];
#pragma unroll
    for (int ni = 0; ni < 2; ++ni)
        bvals[ni] = bias[o * 128 + e0 + ni * 16 + lam];
#pragma unroll
    for (int mi = 0; mi < 2; ++mi)
#pragma unroll
        for (int ni = 0; ni < 2; ++ni)
#pragma unroll
            for (int rr = 0; rr < 4; ++rr) acc[mi][ni][rr] += bvals[ni];

    // ---- BN stats: block-local (block owns all 512 rows of its 32 cols) ----
#pragma unroll
    for (int ni = 0; ni < 2; ++ni) {
        float s = 0.f, q = 0.f;
#pragma unroll
        for (int mi = 0; mi < 2; ++mi)
#pragma unroll
            for (int rr = 0; rr < 4; ++rr) {
                const float v = acc[mi][ni][rr];
                s += v; q += v * v;
            }
        s += __shfl_xor(s, 16); s += __shfl_xor(s, 32);
        q += __shfl_xor(q, 16); q += __shfl_xor(q, 32);
        if (quad == 0) {
            Sred[wave][ni * 16 + lam] = s;
            Qred[wave][ni * 16 + lam] = q;
        }
    }
    __syncthreads();

    if (tid < 32) {
        float s = 0.f, q = 0.f;
#pragma unroll
        for (int w = 0; w < 16; ++w) {
            s += Sred[w][tid];
            q += Qred[w][tid];
        }
        const float mean = s * (1.0f / 512.0f);
        const float var  = q * (1.0f / 512.0f) - mean * mean;
        const float rstd = rsqrtf(var + 1e-5f);
        const float sc   = rstd * gamma[o * 128 + e0 + tid];
        sscale[tid] = sc;
        sshift[tid] = beta[o * 128 + e0 + tid] - mean * sc;
    }
    __syncthreads();

    // ---- normalize + SiLU in-register, store fp32 ----
#pragma unroll
    for (int mi = 0; mi < 2; ++mi) {
        const int rowb = wave * 32 + mi * 16 + quad * 4;
#pragma unroll
        for (int ni = 0; ni < 2; ++ni) {
            const int col = ni * 16 + lam;
            const float sc = sscale[col];
            const float sh = sshift[col];
#pragma unroll
            for (int rr = 0; rr < 4; ++rr) {
                const float xn = acc[mi][ni][rr] * sc + sh;
                const float sg = 1.0f / (1.0f + __expf(-xn));
                out[(rowb + rr) * FEAT + o * 128 + e0 + col] = xn * sg;
            }
        }
    }
}

extern "C" void kernel_launch(void* const* d_in, const int* in_sizes, int n_in,
                              void* d_out, int out_size, void* d_ws, size_t ws_size,
                              hipStream_t stream)
{
    const float* x     = (const float*)d_in[0];
    const float* W     = (const float*)d_in[1];
    const float* bias  = (const float*)d_in[2];
    const float* gamma = (const float*)d_in[3];
    const float* beta  = (const float*)d_in[4];
    const int*   idx   = (const int*)d_in[5];
    float* out = (float*)d_out;

    fused_encoder<<<dim3(256), dim3(1024), 0, stream>>>(
        x, W, bias, gamma, beta, idx, out);
}